// Round 11
// baseline (302.793 us; speedup 1.0000x reference)
//
#include <hip/hip_runtime.h>
#include <stdint.h>

#define T_ 2048
#define C_ 2048
#define HD 128
#define LDQKV 3072

typedef unsigned short u16;
typedef __attribute__((ext_vector_type(8))) short bf16x8;   // 8 bf16 (4 VGPRs)
typedef __attribute__((ext_vector_type(4))) float f32x4;
typedef __attribute__((ext_vector_type(4))) float float4v;
typedef __attribute__((ext_vector_type(4))) u16 u16x4;
typedef __attribute__((ext_vector_type(8))) u16 u16x8;

typedef __attribute__((address_space(3))) void lds_void;
typedef const __attribute__((address_space(1))) void gbl_void;

__device__ __forceinline__ void gload_lds16(const void* g, void* l) {
  __builtin_amdgcn_global_load_lds((gbl_void*)(uintptr_t)g,
                                   (lds_void*)(uint32_t)(uintptr_t)l, 16, 0, 0);
}

__device__ __forceinline__ u16 f2bf(float f) {
  union { float f; uint32_t u; } v; v.f = f;
  uint32_t r = v.u + 0x7FFFu + ((v.u >> 16) & 1u);
  return (u16)(r >> 16);
}
__device__ __forceinline__ float bf2f(u16 h) {
  union { uint32_t u; float f; } v; v.u = ((uint32_t)h) << 16;
  return v.f;
}

// raw barrier (NOT __syncthreads: that drains vmcnt(0) and kills the pipeline)
#define BAR() do { asm volatile("" ::: "memory"); __builtin_amdgcn_s_barrier(); asm volatile("" ::: "memory"); } while (0)
#define VMCNT(n) asm volatile("s_waitcnt vmcnt(" #n ")" ::: "memory")
// inline-asm immediates must be LITERALS (R8 lesson) -> constexpr dispatch
template<int N> __device__ __forceinline__ void VMCNT_C() {
  if constexpr (N == 0) { VMCNT(0); }
  else if constexpr (N == 3) { VMCNT(3); }
  else if constexpr (N == 4) { VMCNT(4); }
  else { static_assert(N == 0 || N == 3 || N == 4, "add literal"); }
}

// ---------- merged prep: conv_x | wt_qkv transpose | wo_t transpose | cos/sin ----------
__device__ __forceinline__ void ttile(const float* __restrict__ src, int ldw, int nb,
                                      int k0, int n0out, u16* __restrict__ out, int tid,
                                      float (*Lt)[68]) {
  int kr = tid >> 4, nc = (tid & 15) * 4;
#pragma unroll
  for (int s = 0; s < 4; ++s) {
    float4v v = *(const float4v*)(src + (size_t)(k0 + kr + 16 * s) * ldw + nb + nc);
#pragma unroll
    for (int e = 0; e < 4; ++e) Lt[kr + 16 * s][nc + e] = v[e];
  }
  __syncthreads();
  int nr = tid & 31, kc = (tid >> 5) * 8;
#pragma unroll
  for (int s2 = 0; s2 < 2; ++s2) {
    int n = nr + 32 * s2;
    u16x8 o;
#pragma unroll
    for (int e = 0; e < 8; ++e) o[e] = f2bf(Lt[kc + e][n]);
    *(u16x8*)(out + (size_t)(n0out + n) * 2048 + k0 + kc) = o;
  }
}

__global__ __launch_bounds__(256) void k_prep(const float* __restrict__ x,
                                              const float* __restrict__ Wq, const float* __restrict__ Wk,
                                              const float* __restrict__ Wv, const float* __restrict__ Wo,
                                              u16* __restrict__ xbf, u16* __restrict__ wtq,
                                              u16* __restrict__ wot, float* __restrict__ cst) {
  __shared__ float Lt[64][68];
  const int bid = blockIdx.x, tid = threadIdx.x;
  if (bid < 16384) {                                  // x -> bf16
    size_t idx = (size_t)bid * 256 + tid;
    float4v xv = *(const float4v*)(x + idx * 4);
    u16x4 r;
#pragma unroll
    for (int e = 0; e < 4; ++e) r[e] = f2bf(xv[e]);
    *(u16x4*)(xbf + idx * 4) = r;
  } else if (bid < 17920) {                           // wt_qkv: [Wq|Wk|Wv]^T
    int b = bid - 16384;
    int n0 = (b % 48) * 64, k0 = (b / 48) * 64;
    const float* src; int ldw, nb;
    if (n0 < 2048)      { src = Wq; ldw = 2048; nb = n0; }
    else if (n0 < 2560) { src = Wk; ldw = 512;  nb = n0 - 2048; }
    else                { src = Wv; ldw = 512;  nb = n0 - 2560; }
    ttile(src, ldw, nb, k0, n0, wtq, tid, Lt);
  } else if (bid < 18944) {                           // wo^T
    int b = bid - 17920;
    ttile(Wo, 2048, (b % 32) * 64, (b / 32) * 64, (b % 32) * 64, wot, tid, Lt);
  } else {                                            // cos/sin table
    int idx = (bid - 18944) * 256 + tid;              // 131072
    int t = idx >> 6, d = idx & 63;
    float inv = expf(-(float)d * (1.0f / 64.0f) * 9.2103403719761836f);
    float f = (float)t * inv;
    float s, c;
    sincosf(f, &s, &c);
    cst[idx * 2] = c;
    cst[idx * 2 + 1] = s;
  }
}

// ---------- 256xBN 2-phase GEMM, strength-reduced addressing, optional fused RoPE ----------
// Schedule identical to R10 (2 phases/tile, stagger A(t+1)/B(t+2), gate VMCNT(NF)).
// ROPE=1 (GEMM1): q/k columns are INTERLEAVED in the output space: logical col 2d/2d+1
// of a head hold original d / d+64. Permutation applied for free via per-thread B-stage
// source-row remap (row fixed per thread; k-advance += 64 unaffected). QK^T is invariant
// to a shared q/k column permutation, so k_attn is unchanged. Epilogue applies rope
// register-locally: partner via __shfl_xor(a,1) (pair = adjacent lanes, same row),
// out_even = x1*c - x2*s, out_odd = x1*s + x2*c, *1/sqrt(128) for q cols.
template<int OUTF32, int NF, int ROPE>
__global__ __launch_bounds__(512, 1) void k_gemm8(const u16* __restrict__ A, const u16* __restrict__ Bt,
                                                  void* __restrict__ Cout, const float* __restrict__ cst,
                                                  int M, int N, int K, int nbx) {
  constexpr int BUFE = 16384 + NF * 4096;   // u16 elems/buffer (A 256x64 + B NF*64x64)
  __shared__ __attribute__((aligned(16))) u16 lds[2 * BUFE];
  const int tid = threadIdx.x, lane = tid & 63;
  const int w = tid >> 6, wm = w >> 2, wn = w & 3;
  const int l15 = lane & 15, lhi = lane >> 4;
  const int nwg = gridDim.x, cpx = nwg >> 3;
  const int wg = (blockIdx.x & 7) * cpx + (blockIdx.x >> 3);
  const int bx = wg % nbx, by = wg / nbx;
  const int m0 = by * 256, n0 = bx * (NF * 64);
  const int NT = K >> 6;

  // interleave permutation: output row n sources original row prow(n)
  auto prow = [&](int n) -> int {
    if constexpr (ROPE) {
      if (n < 2560) { int hc = n & 127; return (n & ~127) | ((hc >> 1) + ((hc & 1) << 6)); }
    }
    return n;
  };

  // ---- staging pointers (per-thread, advanced +64 elems per staged tile)
  const int srow = tid >> 3;
  const int scol = ((tid & 7) ^ (srow & 7)) * 8;   // pre-swizzled global col
  const u16* pA0 = A + (size_t)(m0 + srow) * K + scol;
  const u16* pA1 = pA0 + (size_t)64 * K;
  const u16* pA2 = pA0 + (size_t)128 * K;
  const u16* pA3 = pA0 + (size_t)192 * K;
  const u16* pB0 = Bt + (size_t)prow(n0 + srow) * K + scol;
  const u16* pB1 = Bt + (size_t)prow(n0 + 64 + srow) * K + scol;
  const u16* pB2 = Bt + (size_t)prow(n0 + 128 + srow) * K + scol;
  const u16* pB3 = Bt + (size_t)prow(n0 + (NF == 4 ? 192 : 128) + srow) * K + scol;
  // LDS dst bases (unit u -> + u*4096)
  u16* dEA = lds + tid * 8;
  u16* dEB = lds + 16384 + tid * 8;
  u16* dOA = lds + BUFE + tid * 8;
  u16* dOB = lds + BUFE + 16384 + tid * 8;
  // ds_read bases: {A,B} x {ks0,ks1} x {E,O}; fragment offs are literals
  const int xk0 = (lhi ^ (l15 & 7)) * 8;
  const int xk1 = ((4 + lhi) ^ (l15 & 7)) * 8;
  const u16* rAe0 = lds + (wm * 128 + l15) * 64 + xk0;
  const u16* rAe1 = lds + (wm * 128 + l15) * 64 + xk1;
  const u16* rBe0 = lds + 16384 + (wn * (NF * 16) + l15) * 64 + xk0;
  const u16* rBe1 = lds + 16384 + (wn * (NF * 16) + l15) * 64 + xk1;
  const u16* rAo0 = rAe0 + BUFE;
  const u16* rAo1 = rAe1 + BUFE;
  const u16* rBo0 = rBe0 + BUFE;
  const u16* rBo1 = rBe1 + BUFE;

  f32x4 acc[8][NF];
#pragma unroll
  for (int i = 0; i < 8; ++i)
#pragma unroll
    for (int j = 0; j < NF; ++j) acc[i][j] = (f32x4){0.f, 0.f, 0.f, 0.f};

  // prologue: tile0 (A+B) -> E; B(t1) -> O.B; drain tile0, keep B(t1) in flight
  gload_lds16(pA0, dEA);         gload_lds16(pA1, dEA + 4096);
  gload_lds16(pA2, dEA + 8192);  gload_lds16(pA3, dEA + 12288);
  gload_lds16(pB0, dEB);         gload_lds16(pB1, dEB + 4096);
  gload_lds16(pB2, dEB + 8192);
  if constexpr (NF == 4) gload_lds16(pB3, dEB + 12288);
  pB0 += 64; pB1 += 64; pB2 += 64;
  if constexpr (NF == 4) pB3 += 64;
  gload_lds16(pB0, dOB);         gload_lds16(pB1, dOB + 4096);
  gload_lds16(pB2, dOB + 8192);
  if constexpr (NF == 4) gload_lds16(pB3, dOB + 12288);
  VMCNT_C<NF>();
  BAR();

  // one K-tile body; parity resolved by caller via named pointers
  auto TILE = [&](const u16* rA0, const u16* rA1, const u16* rB0, const u16* rB1,
                  u16* dA, u16* dB, bool stA, bool nlast) {
    bf16x8 bb[NF][2], aa[4][2];
    auto MH = [&](int h) {   // acc rows h*4..h*4+3 x all nf, ks-outer
#pragma unroll
      for (int ks = 0; ks < 2; ++ks)
#pragma unroll
        for (int mi = 0; mi < 4; ++mi)
#pragma unroll
          for (int nf = 0; nf < NF; ++nf)
            acc[h * 4 + mi][nf] = __builtin_amdgcn_mfma_f32_16x16x32_bf16(
                aa[mi][ks], bb[nf][ks], acc[h * 4 + mi][nf], 0, 0, 0);
    };
    // phA: read bb + af[0-3]; stage A(t+1); MFMA mf0-3
#pragma unroll
    for (int nf = 0; nf < NF; ++nf) {
      bb[nf][0] = *(const bf16x8*)(rB0 + nf * 1024);
      bb[nf][1] = *(const bf16x8*)(rB1 + nf * 1024);
    }
#pragma unroll
    for (int mi = 0; mi < 4; ++mi) {
      aa[mi][0] = *(const bf16x8*)(rA0 + mi * 1024);
      aa[mi][1] = *(const bf16x8*)(rA1 + mi * 1024);
    }
    if (stA) {
      pA0 += 64; pA1 += 64; pA2 += 64; pA3 += 64;
      gload_lds16(pA0, dA);        gload_lds16(pA1, dA + 4096);
      gload_lds16(pA2, dA + 8192); gload_lds16(pA3, dA + 12288);
    }
    __builtin_amdgcn_s_setprio(1);
    MH(0);
    __builtin_amdgcn_s_setprio(0);
    BAR();
    // phB: read af[4-7]; stage B(t+2); MFMA mf4-7; gate; BAR
#pragma unroll
    for (int mi = 0; mi < 4; ++mi) {
      aa[mi][0] = *(const bf16x8*)(rA0 + 4096 + mi * 1024);
      aa[mi][1] = *(const bf16x8*)(rA1 + 4096 + mi * 1024);
    }
    if (nlast) {
      pB0 += 64; pB1 += 64; pB2 += 64;
      gload_lds16(pB0, dB);        gload_lds16(pB1, dB + 4096);
      gload_lds16(pB2, dB + 8192);
      if constexpr (NF == 4) { pB3 += 64; gload_lds16(pB3, dB + 12288); }
    }
    __builtin_amdgcn_s_setprio(1);
    MH(1);
    __builtin_amdgcn_s_setprio(0);
    if (nlast) { VMCNT_C<NF>(); } else { VMCNT_C<0>(); }
    BAR();
  };

  for (int t = 0; t < NT; t += 2) {
    const bool nlast = (t + 2 < NT);
    TILE(rAe0, rAe1, rBe0, rBe1, dOA, dEB, true,  nlast);   // tile t   (E)
    TILE(rAo0, rAo1, rBo0, rBo1, dEA, dOB, nlast, nlast);   // tile t+1 (O)
  }

  // epilogue: rows m0+wm*128+mf*16+lhi*4+r, cols n0+wn*(NF*16)+nf*16+l15
#pragma unroll
  for (int mf = 0; mf < 8; ++mf) {
#pragma unroll
    for (int nf = 0; nf < NF; ++nf) {
      int col = n0 + wn * (NF * 16) + nf * 16 + l15;
      bool qk = false;
      float sc = 1.0f, sgn = 1.0f;
      int dcol = 0;
      if constexpr (ROPE) {
        qk = (col < 2560);                       // wave-uniform per fragment (16|2560)
        sc = (col < 2048) ? 0.08838834764831845f : 1.0f;
        sgn = (col & 1) ? 1.0f : -1.0f;
        dcol = (col & 127) >> 1;
      }
#pragma unroll
      for (int r = 0; r < 4; ++r) {
        int row = m0 + wm * 128 + mf * 16 + lhi * 4 + r;
        float a = acc[mf][nf][r];
        float v = a;
        if constexpr (ROPE) {
          if (qk) {
            float b = __shfl_xor(a, 1);          // partner col (same row: lhi untouched)
            const float* cp = cst + (size_t)(((row & 2047) << 6) + dcol) * 2;
            v = (a * cp[0] + b * sgn * cp[1]) * sc;
          }
        }
        if (OUTF32) ((float*)Cout)[(size_t)row * N + col] = v;
        else        ((u16*)Cout)[(size_t)row * N + col] = f2bf(v);
      }
    }
  }
}

// ---------- windowed flash attention (swizzled, conflict-free; unchanged) ----------
// NOTE: q/k columns are interleave-permuted by GEMM1; QK^T dot over d is invariant
// since q and k share the same intra-head permutation. V columns untouched.
__global__ __launch_bounds__(256) void k_attn(const u16* __restrict__ qkv, u16* __restrict__ y) {
  const int bid = blockIdx.x;
  const int qt = bid & 31, h = (bid >> 5) & 15, b = bid >> 9;
  const int i0 = qt * 64;
  const size_t tb = (size_t)b * T_ * LDQKV;
  const u16* qb = qkv + tb + h * HD;
  const u16* kb = qkv + tb + 2048 + (h >> 2) * HD;
  const u16* vb = kb + 512;
  __shared__ __attribute__((aligned(16))) u16 smem[20480];   // 40 KB
  u16* Ks = smem;
  u16* Vt = smem + 8192;
  u16* Psw = smem + 16384;
  u16* Qs = smem;
  const int tid = threadIdx.x, lane = tid & 63, w = tid >> 6;
  const int l15 = lane & 15, lhi = lane >> 4;
  u16* Ps = Psw + w * 1024;

#pragma unroll
  for (int it = 0; it < 4; ++it) {
    int c = it * 256 + tid, row = c >> 4, kc = (c & 15) ^ (row & 7);
    gload_lds16(qb + (size_t)(i0 + row) * LDQKV + kc * 8, &Qs[(it * 256 + w * 64) * 8]);
  }
  __syncthreads();
  bf16x8 qf[4];
#pragma unroll
  for (int ks = 0; ks < 4; ++ks) {
    int row = w * 16 + l15;
    int kc = (ks * 4 + lhi) ^ (row & 7);
    qf[ks] = *(const bf16x8*)&Qs[(row * 16 + kc) * 8];
  }
  __syncthreads();

  f32x4 o[8];
#pragma unroll
  for (int dt = 0; dt < 8; ++dt) o[dt] = (f32x4){0.f, 0.f, 0.f, 0.f};
  float mrun[4], lrun[4];
#pragma unroll
  for (int r = 0; r < 4; ++r) { mrun[r] = -1e30f; lrun[r] = 0.f; }

  const int jb0 = (i0 >= 256) ? (i0 - 256) : 0;
  for (int jb = jb0; jb <= i0; jb += 64) {
#pragma unroll
    for (int it = 0; it < 4; ++it) {
      int c = it * 256 + tid, row = c >> 4, kc = (c & 15) ^ (row & 7);
      gload_lds16(kb + (size_t)(jb + row) * LDQKV + kc * 8, &Ks[(it * 256 + w * 64) * 8]);
    }
#pragma unroll
    for (int it = 0; it < 4; ++it) {
      int chunk = it * 256 + tid, row = chunk >> 4, dc = chunk & 15;
      u16x8 vv = *(const u16x8*)(vb + (size_t)(jb + row) * LDQKV + dc * 8);
#pragma unroll
      for (int e = 0; e < 8; ++e) {
        int d = dc * 8 + e;
        int s = (dc ^ e) & 7;
        Vt[d * 64 + (row ^ (s << 3))] = vv[e];
      }
    }
    __syncthreads();

    f32x4 s[4];
#pragma unroll
    for (int t = 0; t < 4; ++t) {
      s[t] = (f32x4){0.f, 0.f, 0.f, 0.f};
#pragma unroll
      for (int ks = 0; ks < 4; ++ks) {
        int row = t * 16 + l15;
        int kc = (ks * 4 + lhi) ^ (row & 7);
        bf16x8 kf = *(const bf16x8*)&Ks[(row * 16 + kc) * 8];
        s[t] = __builtin_amdgcn_mfma_f32_16x16x32_bf16(qf[ks], kf, s[t], 0, 0, 0);
      }
    }

    const int irow0 = i0 + w * 16 + lhi * 4;
    float rmax[4];
#pragma unroll
    for (int r = 0; r < 4; ++r) rmax[r] = -1e30f;
#pragma unroll
    for (int t = 0; t < 4; ++t) {
      int j = jb + t * 16 + l15;
#pragma unroll
      for (int r = 0; r < 4; ++r) {
        int i = irow0 + r;
        float sv = s[t][r];
        sv = (j <= i && j + 256 >= i) ? sv : -1e30f;
        s[t][r] = sv;
        rmax[r] = fmaxf(rmax[r], sv);
      }
    }
#pragma unroll
    for (int r = 0; r < 4; ++r) {
#pragma unroll
      for (int off = 1; off < 16; off <<= 1)
        rmax[r] = fmaxf(rmax[r], __shfl_xor(rmax[r], off));
    }
    float sf[4], psum[4];
#pragma unroll
    for (int r = 0; r < 4; ++r) {
      float mn = fmaxf(mrun[r], rmax[r]);
      sf[r] = __expf(mrun[r] - mn);
      mrun[r] = mn;
      psum[r] = 0.f;
    }
#pragma unroll
    for (int t = 0; t < 4; ++t) {
#pragma unroll
      for (int r = 0; r < 4; ++r) {
        float p = __expf(s[t][r] - mrun[r]);
        psum[r] += p;
        int q = lhi * 4 + r;
        int k = t * 16 + l15;
        Ps[q * 64 + (k ^ ((q & 7) << 3))] = f2bf(p);
      }
    }
#pragma unroll
    for (int r = 0; r < 4; ++r) {
#pragma unroll
      for (int off = 1; off < 16; off <<= 1)
        psum[r] += __shfl_xor(psum[r], off);
      lrun[r] = lrun[r] * sf[r] + psum[r];
    }
#pragma unroll
    for (int dt = 0; dt < 8; ++dt)
#pragma unroll
      for (int r = 0; r < 4; ++r)
        o[dt][r] = o[dt][r] * sf[r];

    bf16x8 pf[2];
#pragma unroll
    for (int ks2 = 0; ks2 < 2; ++ks2)
      pf[ks2] = *(const bf16x8*)&Ps[l15 * 64 + ((ks2 * 32 + lhi * 8) ^ ((l15 & 7) << 3))];
#pragma unroll
    for (int dt = 0; dt < 8; ++dt) {
#pragma unroll
      for (int ks2 = 0; ks2 < 2; ++ks2) {
        int d = dt * 16 + l15;
        int s2 = ((d >> 3) ^ (d & 7)) & 7;
        bf16x8 vf = *(const bf16x8*)&Vt[d * 64 + ((ks2 * 32 + lhi * 8) ^ (s2 << 3))];
        o[dt] = __builtin_amdgcn_mfma_f32_16x16x32_bf16(pf[ks2], vf, o[dt], 0, 0, 0);
      }
    }
    __syncthreads();
  }

#pragma unroll
  for (int dt = 0; dt < 8; ++dt) {
#pragma unroll
    for (int r = 0; r < 4; ++r) {
      int i = i0 + w * 16 + lhi * 4 + r;
      float v = o[dt][r] / lrun[r];
      y[((size_t)b * T_ + i) * C_ + h * HD + dt * 16 + l15] = f2bf(v);
    }
  }
}

extern "C" void kernel_launch(void* const* d_in, const int* in_sizes, int n_in,
                              void* d_out, int out_size, void* d_ws, size_t ws_size,
                              hipStream_t stream) {
  const float* x  = (const float*)d_in[0];
  const float* Wq = (const float*)d_in[1];
  const float* Wk = (const float*)d_in[2];
  const float* Wv = (const float*)d_in[3];
  const float* Wo = (const float*)d_in[4];
  char* ws = (char*)d_ws;
  u16* x_bf   = (u16*)(ws);                 // 33,554,432 B (reused as y after GEMM1)
  u16* wt_qkv = (u16*)(ws + 33554432);      // 12,582,912 B
  u16* wo_t   = (u16*)(ws + 46137344);      //  8,388,608 B
  u16* qkv    = (u16*)(ws + 54525952);      // 50,331,648 B
  float* cst  = (float*)(ws + 104857600);   //  1,048,576 B
  u16* ybuf = x_bf;

  // merged prep: [0,16384) conv_x | [16384,17920) wt_qkv | [17920,18944) wo_t | [18944,19456) cs
  k_prep<<<19456, 256, 0, stream>>>(x, Wq, Wk, Wv, Wo, x_bf, wt_qkv, wo_t, cst);

  // GEMM1 (fused RoPE via interleaved q/k columns): BN=192, grid 512 = 2 exact rounds
  k_gemm8<0, 3, 1><<<512, 512, 0, stream>>>(x_bf, wt_qkv, (void*)qkv, cst, 8192, 3072, 2048, 16);

  k_attn<<<2048, 256, 0, stream>>>(qkv, ybuf);

  // GEMM2: BN=256 -> grid 256 = 1 exact round
  k_gemm8<1, 4, 0><<<256, 512, 0, stream>>>(ybuf, wo_t, d_out, nullptr, 8192, 2048, 2048, 8);
}

// Round 12
// 286.548 us; speedup vs baseline: 1.0567x; 1.0567x over previous
//
#include <hip/hip_runtime.h>
#include <stdint.h>

#define T_ 2048
#define C_ 2048
#define HD 128
#define LDQKV 3072

typedef unsigned short u16;
typedef __attribute__((ext_vector_type(8))) short bf16x8;   // 8 bf16 (4 VGPRs)
typedef __attribute__((ext_vector_type(4))) float f32x4;
typedef __attribute__((ext_vector_type(4))) float float4v;
typedef __attribute__((ext_vector_type(4))) u16 u16x4;
typedef __attribute__((ext_vector_type(8))) u16 u16x8;

typedef __attribute__((address_space(3))) void lds_void;
typedef const __attribute__((address_space(1))) void gbl_void;

__device__ __forceinline__ void gload_lds16(const void* g, void* l) {
  __builtin_amdgcn_global_load_lds((gbl_void*)(uintptr_t)g,
                                   (lds_void*)(uint32_t)(uintptr_t)l, 16, 0, 0);
}

__device__ __forceinline__ u16 f2bf(float f) {
  union { float f; uint32_t u; } v; v.f = f;
  uint32_t r = v.u + 0x7FFFu + ((v.u >> 16) & 1u);
  return (u16)(r >> 16);
}
__device__ __forceinline__ float bf2f(u16 h) {
  union { uint32_t u; float f; } v; v.u = ((uint32_t)h) << 16;
  return v.f;
}

// raw barrier (NOT __syncthreads: that drains vmcnt(0) and kills the pipeline)
#define BAR() do { asm volatile("" ::: "memory"); __builtin_amdgcn_s_barrier(); asm volatile("" ::: "memory"); } while (0)
#define VMCNT(n) asm volatile("s_waitcnt vmcnt(" #n ")" ::: "memory")
// inline-asm immediates must be LITERALS (R8 lesson) -> constexpr dispatch
template<int N> __device__ __forceinline__ void VMCNT_C() {
  if constexpr (N == 0) { VMCNT(0); }
  else if constexpr (N == 3) { VMCNT(3); }
  else if constexpr (N == 4) { VMCNT(4); }
  else { static_assert(N == 0 || N == 3 || N == 4, "add literal"); }
}

// ---------- merged prep: conv_x | wt_qkv transpose | wo_t transpose | cos/sin ----------
__device__ __forceinline__ void ttile(const float* __restrict__ src, int ldw, int nb,
                                      int k0, int n0out, u16* __restrict__ out, int tid,
                                      float (*Lt)[68]) {
  int kr = tid >> 4, nc = (tid & 15) * 4;
#pragma unroll
  for (int s = 0; s < 4; ++s) {
    float4v v = *(const float4v*)(src + (size_t)(k0 + kr + 16 * s) * ldw + nb + nc);
#pragma unroll
    for (int e = 0; e < 4; ++e) Lt[kr + 16 * s][nc + e] = v[e];
  }
  __syncthreads();
  int nr = tid & 31, kc = (tid >> 5) * 8;
#pragma unroll
  for (int s2 = 0; s2 < 2; ++s2) {
    int n = nr + 32 * s2;
    u16x8 o;
#pragma unroll
    for (int e = 0; e < 8; ++e) o[e] = f2bf(Lt[kc + e][n]);
    *(u16x8*)(out + (size_t)(n0out + n) * 2048 + k0 + kc) = o;
  }
}

__global__ __launch_bounds__(256) void k_prep(const float* __restrict__ x,
                                              const float* __restrict__ Wq, const float* __restrict__ Wk,
                                              const float* __restrict__ Wv, const float* __restrict__ Wo,
                                              u16* __restrict__ xbf, u16* __restrict__ wtq,
                                              u16* __restrict__ wot, float* __restrict__ cst) {
  __shared__ float Lt[64][68];
  const int bid = blockIdx.x, tid = threadIdx.x;
  if (bid < 16384) {                                  // x -> bf16
    size_t idx = (size_t)bid * 256 + tid;
    float4v xv = *(const float4v*)(x + idx * 4);
    u16x4 r;
#pragma unroll
    for (int e = 0; e < 4; ++e) r[e] = f2bf(xv[e]);
    *(u16x4*)(xbf + idx * 4) = r;
  } else if (bid < 17920) {                           // wt_qkv: [Wq|Wk|Wv]^T
    int b = bid - 16384;
    int n0 = (b % 48) * 64, k0 = (b / 48) * 64;
    const float* src; int ldw, nb;
    if (n0 < 2048)      { src = Wq; ldw = 2048; nb = n0; }
    else if (n0 < 2560) { src = Wk; ldw = 512;  nb = n0 - 2048; }
    else                { src = Wv; ldw = 512;  nb = n0 - 2560; }
    ttile(src, ldw, nb, k0, n0, wtq, tid, Lt);
  } else if (bid < 18944) {                           // wo^T
    int b = bid - 17920;
    ttile(Wo, 2048, (b % 32) * 64, (b / 32) * 64, (b % 32) * 64, wot, tid, Lt);
  } else {                                            // cos/sin table
    int idx = (bid - 18944) * 256 + tid;              // 131072
    int t = idx >> 6, d = idx & 63;
    float inv = expf(-(float)d * (1.0f / 64.0f) * 9.2103403719761836f);
    float f = (float)t * inv;
    float s, c;
    sincosf(f, &s, &c);
    cst[idx * 2] = c;
    cst[idx * 2 + 1] = s;
  }
}

// RoPE in place, x8 vectorized; folds 1/sqrt(HD) into q heads.
// (R11 lesson: this kernel is HBM-roofline at ~6.4 TB/s / ~13us; fusing it into
// GEMM1's epilogue cost +32us of latency-exposed scattered loads. Keep standalone.)
__global__ __launch_bounds__(256) void k_rope(u16* __restrict__ qkv, const float* __restrict__ cst) {
  int idx = blockIdx.x * 256 + threadIdx.x;   // 1,310,720
  int token = idx / 160;
  int rem = idx - token * 160;
  int hd = rem >> 3, oct = rem & 7;
  int col = ((hd < 16) ? hd * 128 : 2048 + (hd - 16) * 128) + oct * 8;
  size_t base = (size_t)token * LDQKV + col;
  int t = token & (T_ - 1);
  float sc = (hd < 16) ? 0.08838834764831845f : 1.0f;
  u16x8 a = *(const u16x8*)(qkv + base);
  u16x8 b2 = *(const u16x8*)(qkv + base + 64);
  const float* cp = cst + (size_t)(t * 64 + oct * 8) * 2;
  u16x8 ra, rb;
#pragma unroll
  for (int e = 0; e < 8; ++e) {
    float c = cp[e * 2], s = cp[e * 2 + 1];
    float x1 = bf2f(a[e]), x2 = bf2f(b2[e]);
    ra[e] = f2bf((x1 * c - x2 * s) * sc);
    rb[e] = f2bf((x1 * s + x2 * c) * sc);
  }
  *(u16x8*)(qkv + base) = ra;
  *(u16x8*)(qkv + base + 64) = rb;
}

// ---------- 256xBN 2-phase GEMM, strength-reduced addressing (R10-identical) ----------
// 2 phases/tile, stagger A(t+1)/B(t+2), gate VMCNT(NF). 2 tiles/iteration with
// parity-resolved named pointers -> zero in-loop address VALU (ds_read = base +
// compile-time immediate; global stage ptrs advance += 64/tile).
template<int OUTF32, int NF>
__global__ __launch_bounds__(512, 1) void k_gemm8(const u16* __restrict__ A, const u16* __restrict__ Bt,
                                                  void* __restrict__ Cout, int M, int N, int K, int nbx) {
  constexpr int BUFE = 16384 + NF * 4096;   // u16 elems/buffer (A 256x64 + B NF*64x64)
  __shared__ __attribute__((aligned(16))) u16 lds[2 * BUFE];
  const int tid = threadIdx.x, lane = tid & 63;
  const int w = tid >> 6, wm = w >> 2, wn = w & 3;
  const int l15 = lane & 15, lhi = lane >> 4;
  const int nwg = gridDim.x, cpx = nwg >> 3;
  const int wg = (blockIdx.x & 7) * cpx + (blockIdx.x >> 3);
  const int bx = wg % nbx, by = wg / nbx;
  const int m0 = by * 256, n0 = bx * (NF * 64);
  const int NT = K >> 6;

  // ---- staging pointers (per-thread, advanced +64 elems per staged tile)
  const int srow = tid >> 3;
  const int scol = ((tid & 7) ^ (srow & 7)) * 8;   // pre-swizzled global col
  const u16* pA0 = A + (size_t)(m0 + srow) * K + scol;
  const u16* pA1 = pA0 + (size_t)64 * K;
  const u16* pA2 = pA0 + (size_t)128 * K;
  const u16* pA3 = pA0 + (size_t)192 * K;
  const u16* pB0 = Bt + (size_t)(n0 + srow) * K + scol;
  const u16* pB1 = pB0 + (size_t)64 * K;
  const u16* pB2 = pB0 + (size_t)128 * K;
  const u16* pB3 = pB0 + (size_t)(NF == 4 ? 192 : 128) * K;
  // LDS dst bases (unit u -> + u*4096)
  u16* dEA = lds + tid * 8;
  u16* dEB = lds + 16384 + tid * 8;
  u16* dOA = lds + BUFE + tid * 8;
  u16* dOB = lds + BUFE + 16384 + tid * 8;
  // ds_read bases: {A,B} x {ks0,ks1} x {E,O}; fragment offs are literals
  const int xk0 = (lhi ^ (l15 & 7)) * 8;
  const int xk1 = ((4 + lhi) ^ (l15 & 7)) * 8;
  const u16* rAe0 = lds + (wm * 128 + l15) * 64 + xk0;
  const u16* rAe1 = lds + (wm * 128 + l15) * 64 + xk1;
  const u16* rBe0 = lds + 16384 + (wn * (NF * 16) + l15) * 64 + xk0;
  const u16* rBe1 = lds + 16384 + (wn * (NF * 16) + l15) * 64 + xk1;
  const u16* rAo0 = rAe0 + BUFE;
  const u16* rAo1 = rAe1 + BUFE;
  const u16* rBo0 = rBe0 + BUFE;
  const u16* rBo1 = rBe1 + BUFE;

  f32x4 acc[8][NF];
#pragma unroll
  for (int i = 0; i < 8; ++i)
#pragma unroll
    for (int j = 0; j < NF; ++j) acc[i][j] = (f32x4){0.f, 0.f, 0.f, 0.f};

  // prologue: tile0 (A+B) -> E; B(t1) -> O.B; drain tile0, keep B(t1) in flight
  gload_lds16(pA0, dEA);         gload_lds16(pA1, dEA + 4096);
  gload_lds16(pA2, dEA + 8192);  gload_lds16(pA3, dEA + 12288);
  gload_lds16(pB0, dEB);         gload_lds16(pB1, dEB + 4096);
  gload_lds16(pB2, dEB + 8192);
  if constexpr (NF == 4) gload_lds16(pB3, dEB + 12288);
  pB0 += 64; pB1 += 64; pB2 += 64;
  if constexpr (NF == 4) pB3 += 64;
  gload_lds16(pB0, dOB);         gload_lds16(pB1, dOB + 4096);
  gload_lds16(pB2, dOB + 8192);
  if constexpr (NF == 4) gload_lds16(pB3, dOB + 12288);
  VMCNT_C<NF>();
  BAR();

  // one K-tile body; parity resolved by caller via named pointers
  auto TILE = [&](const u16* rA0, const u16* rA1, const u16* rB0, const u16* rB1,
                  u16* dA, u16* dB, bool stA, bool nlast) {
    bf16x8 bb[NF][2], aa[4][2];
    auto MH = [&](int h) {   // acc rows h*4..h*4+3 x all nf, ks-outer
#pragma unroll
      for (int ks = 0; ks < 2; ++ks)
#pragma unroll
        for (int mi = 0; mi < 4; ++mi)
#pragma unroll
          for (int nf = 0; nf < NF; ++nf)
            acc[h * 4 + mi][nf] = __builtin_amdgcn_mfma_f32_16x16x32_bf16(
                aa[mi][ks], bb[nf][ks], acc[h * 4 + mi][nf], 0, 0, 0);
    };
    // phA: read bb + af[0-3]; stage A(t+1); MFMA mf0-3
#pragma unroll
    for (int nf = 0; nf < NF; ++nf) {
      bb[nf][0] = *(const bf16x8*)(rB0 + nf * 1024);
      bb[nf][1] = *(const bf16x8*)(rB1 + nf * 1024);
    }
#pragma unroll
    for (int mi = 0; mi < 4; ++mi) {
      aa[mi][0] = *(const bf16x8*)(rA0 + mi * 1024);
      aa[mi][1] = *(const bf16x8*)(rA1 + mi * 1024);
    }
    if (stA) {
      pA0 += 64; pA1 += 64; pA2 += 64; pA3 += 64;
      gload_lds16(pA0, dA);        gload_lds16(pA1, dA + 4096);
      gload_lds16(pA2, dA + 8192); gload_lds16(pA3, dA + 12288);
    }
    __builtin_amdgcn_s_setprio(1);
    MH(0);
    __builtin_amdgcn_s_setprio(0);
    BAR();
    // phB: read af[4-7]; stage B(t+2); MFMA mf4-7; gate; BAR
#pragma unroll
    for (int mi = 0; mi < 4; ++mi) {
      aa[mi][0] = *(const bf16x8*)(rA0 + 4096 + mi * 1024);
      aa[mi][1] = *(const bf16x8*)(rA1 + 4096 + mi * 1024);
    }
    if (nlast) {
      pB0 += 64; pB1 += 64; pB2 += 64;
      gload_lds16(pB0, dB);        gload_lds16(pB1, dB + 4096);
      gload_lds16(pB2, dB + 8192);
      if constexpr (NF == 4) { pB3 += 64; gload_lds16(pB3, dB + 12288); }
    }
    __builtin_amdgcn_s_setprio(1);
    MH(1);
    __builtin_amdgcn_s_setprio(0);
    if (nlast) { VMCNT_C<NF>(); } else { VMCNT_C<0>(); }
    BAR();
  };

  for (int t = 0; t < NT; t += 2) {
    const bool nlast = (t + 2 < NT);
    TILE(rAe0, rAe1, rBe0, rBe1, dOA, dEB, true,  nlast);   // tile t   (E)
    TILE(rAo0, rAo1, rBo0, rBo1, dEA, dOB, nlast, nlast);   // tile t+1 (O)
  }

  // epilogue: rows m0+wm*128+mf*16+lhi*4+r, cols n0+wn*(NF*16)+nf*16+l15
#pragma unroll
  for (int mf = 0; mf < 8; ++mf) {
#pragma unroll
    for (int nf = 0; nf < NF; ++nf) {
      int col = n0 + wn * (NF * 16) + nf * 16 + l15;
#pragma unroll
      for (int r = 0; r < 4; ++r) {
        int row = m0 + wm * 128 + mf * 16 + lhi * 4 + r;
        float v = acc[mf][nf][r];
        if (OUTF32) ((float*)Cout)[(size_t)row * N + col] = v;
        else        ((u16*)Cout)[(size_t)row * N + col] = f2bf(v);
      }
    }
  }
}

// ---------- windowed flash attention (swizzled, conflict-free; unchanged) ----------
__global__ __launch_bounds__(256) void k_attn(const u16* __restrict__ qkv, u16* __restrict__ y) {
  const int bid = blockIdx.x;
  const int qt = bid & 31, h = (bid >> 5) & 15, b = bid >> 9;
  const int i0 = qt * 64;
  const size_t tb = (size_t)b * T_ * LDQKV;
  const u16* qb = qkv + tb + h * HD;
  const u16* kb = qkv + tb + 2048 + (h >> 2) * HD;
  const u16* vb = kb + 512;
  __shared__ __attribute__((aligned(16))) u16 smem[20480];   // 40 KB
  u16* Ks = smem;
  u16* Vt = smem + 8192;
  u16* Psw = smem + 16384;
  u16* Qs = smem;
  const int tid = threadIdx.x, lane = tid & 63, w = tid >> 6;
  const int l15 = lane & 15, lhi = lane >> 4;
  u16* Ps = Psw + w * 1024;

#pragma unroll
  for (int it = 0; it < 4; ++it) {
    int c = it * 256 + tid, row = c >> 4, kc = (c & 15) ^ (row & 7);
    gload_lds16(qb + (size_t)(i0 + row) * LDQKV + kc * 8, &Qs[(it * 256 + w * 64) * 8]);
  }
  __syncthreads();
  bf16x8 qf[4];
#pragma unroll
  for (int ks = 0; ks < 4; ++ks) {
    int row = w * 16 + l15;
    int kc = (ks * 4 + lhi) ^ (row & 7);
    qf[ks] = *(const bf16x8*)&Qs[(row * 16 + kc) * 8];
  }
  __syncthreads();

  f32x4 o[8];
#pragma unroll
  for (int dt = 0; dt < 8; ++dt) o[dt] = (f32x4){0.f, 0.f, 0.f, 0.f};
  float mrun[4], lrun[4];
#pragma unroll
  for (int r = 0; r < 4; ++r) { mrun[r] = -1e30f; lrun[r] = 0.f; }

  const int jb0 = (i0 >= 256) ? (i0 - 256) : 0;
  for (int jb = jb0; jb <= i0; jb += 64) {
#pragma unroll
    for (int it = 0; it < 4; ++it) {
      int c = it * 256 + tid, row = c >> 4, kc = (c & 15) ^ (row & 7);
      gload_lds16(kb + (size_t)(jb + row) * LDQKV + kc * 8, &Ks[(it * 256 + w * 64) * 8]);
    }
#pragma unroll
    for (int it = 0; it < 4; ++it) {
      int chunk = it * 256 + tid, row = chunk >> 4, dc = chunk & 15;
      u16x8 vv = *(const u16x8*)(vb + (size_t)(jb + row) * LDQKV + dc * 8);
#pragma unroll
      for (int e = 0; e < 8; ++e) {
        int d = dc * 8 + e;
        int s = (dc ^ e) & 7;
        Vt[d * 64 + (row ^ (s << 3))] = vv[e];
      }
    }
    __syncthreads();

    f32x4 s[4];
#pragma unroll
    for (int t = 0; t < 4; ++t) {
      s[t] = (f32x4){0.f, 0.f, 0.f, 0.f};
#pragma unroll
      for (int ks = 0; ks < 4; ++ks) {
        int row = t * 16 + l15;
        int kc = (ks * 4 + lhi) ^ (row & 7);
        bf16x8 kf = *(const bf16x8*)&Ks[(row * 16 + kc) * 8];
        s[t] = __builtin_amdgcn_mfma_f32_16x16x32_bf16(qf[ks], kf, s[t], 0, 0, 0);
      }
    }

    const int irow0 = i0 + w * 16 + lhi * 4;
    float rmax[4];
#pragma unroll
    for (int r = 0; r < 4; ++r) rmax[r] = -1e30f;
#pragma unroll
    for (int t = 0; t < 4; ++t) {
      int j = jb + t * 16 + l15;
#pragma unroll
      for (int r = 0; r < 4; ++r) {
        int i = irow0 + r;
        float sv = s[t][r];
        sv = (j <= i && j + 256 >= i) ? sv : -1e30f;
        s[t][r] = sv;
        rmax[r] = fmaxf(rmax[r], sv);
      }
    }
#pragma unroll
    for (int r = 0; r < 4; ++r) {
#pragma unroll
      for (int off = 1; off < 16; off <<= 1)
        rmax[r] = fmaxf(rmax[r], __shfl_xor(rmax[r], off));
    }
    float sf[4], psum[4];
#pragma unroll
    for (int r = 0; r < 4; ++r) {
      float mn = fmaxf(mrun[r], rmax[r]);
      sf[r] = __expf(mrun[r] - mn);
      mrun[r] = mn;
      psum[r] = 0.f;
    }
#pragma unroll
    for (int t = 0; t < 4; ++t) {
#pragma unroll
      for (int r = 0; r < 4; ++r) {
        float p = __expf(s[t][r] - mrun[r]);
        psum[r] += p;
        int q = lhi * 4 + r;
        int k = t * 16 + l15;
        Ps[q * 64 + (k ^ ((q & 7) << 3))] = f2bf(p);
      }
    }
#pragma unroll
    for (int r = 0; r < 4; ++r) {
#pragma unroll
      for (int off = 1; off < 16; off <<= 1)
        psum[r] += __shfl_xor(psum[r], off);
      lrun[r] = lrun[r] * sf[r] + psum[r];
    }
#pragma unroll
    for (int dt = 0; dt < 8; ++dt)
#pragma unroll
      for (int r = 0; r < 4; ++r)
        o[dt][r] = o[dt][r] * sf[r];

    bf16x8 pf[2];
#pragma unroll
    for (int ks2 = 0; ks2 < 2; ++ks2)
      pf[ks2] = *(const bf16x8*)&Ps[l15 * 64 + ((ks2 * 32 + lhi * 8) ^ ((l15 & 7) << 3))];
#pragma unroll
    for (int dt = 0; dt < 8; ++dt) {
#pragma unroll
      for (int ks2 = 0; ks2 < 2; ++ks2) {
        int d = dt * 16 + l15;
        int s2 = ((d >> 3) ^ (d & 7)) & 7;
        bf16x8 vf = *(const bf16x8*)&Vt[d * 64 + ((ks2 * 32 + lhi * 8) ^ (s2 << 3))];
        o[dt] = __builtin_amdgcn_mfma_f32_16x16x32_bf16(pf[ks2], vf, o[dt], 0, 0, 0);
      }
    }
    __syncthreads();
  }

#pragma unroll
  for (int dt = 0; dt < 8; ++dt) {
#pragma unroll
    for (int r = 0; r < 4; ++r) {
      int i = i0 + w * 16 + lhi * 4 + r;
      float v = o[dt][r] / lrun[r];
      y[((size_t)b * T_ + i) * C_ + h * HD + dt * 16 + l15] = f2bf(v);
    }
  }
}

extern "C" void kernel_launch(void* const* d_in, const int* in_sizes, int n_in,
                              void* d_out, int out_size, void* d_ws, size_t ws_size,
                              hipStream_t stream) {
  const float* x  = (const float*)d_in[0];
  const float* Wq = (const float*)d_in[1];
  const float* Wk = (const float*)d_in[2];
  const float* Wv = (const float*)d_in[3];
  const float* Wo = (const float*)d_in[4];
  char* ws = (char*)d_ws;
  u16* x_bf   = (u16*)(ws);                 // 33,554,432 B (reused as y after GEMM1)
  u16* wt_qkv = (u16*)(ws + 33554432);      // 12,582,912 B
  u16* wo_t   = (u16*)(ws + 46137344);      //  8,388,608 B
  u16* qkv    = (u16*)(ws + 54525952);      // 50,331,648 B
  float* cst  = (float*)(ws + 104857600);   //  1,048,576 B
  u16* ybuf = x_bf;

  // merged prep: [0,16384) conv_x | [16384,17920) wt_qkv | [17920,18944) wo_t | [18944,19456) cs
  k_prep<<<19456, 256, 0, stream>>>(x, Wq, Wk, Wv, Wo, x_bf, wt_qkv, wo_t, cst);

  // GEMM1: BN=192 -> grid 512 = 2 exact rounds (R10 structure, no fusion)
  k_gemm8<0, 3><<<512, 512, 0, stream>>>(x_bf, wt_qkv, (void*)qkv, 8192, 3072, 2048, 16);

  k_rope<<<5120, 256, 0, stream>>>(qkv, cst);
  k_attn<<<2048, 256, 0, stream>>>(qkv, ybuf);

  // GEMM2: BN=256 -> grid 256 = 1 exact round
  k_gemm8<1, 4><<<256, 512, 0, stream>>>(ybuf, wo_t, d_out, 8192, 2048, 2048, 8);
}